// Round 1
// baseline (42.338 us; speedup 1.0000x reference)
//
#include <hip/hip_runtime.h>
#include <hip/hip_bf16.h>

// Problem: in_frame [B=4, C=3, H=512, W=512] float32, scale_factor = 4.
// out [4, 3, 2048, 2048] float32, out[b,c,ho,wo] = in[b,c,ho/4,wo/4].
//
// With s=4, output float4 #v (16B-aligned) covers wo = 4*wo4..4*wo4+3,
// all mapping to input pixel (ho>>2, wo4). One scalar load -> one float4 store.
//
// Constants (all power of 2):
//   W_out/4 = 512  -> wo4 = v & 511,  rest = v >> 9
//   H_out   = 2048 -> ho  = rest & 2047, bc = rest >> 11
//   input plane = 512*512 = 1<<18, input row stride = 512 = 1<<9

__global__ void upscale4x_kernel(const float* __restrict__ in,
                                 float* __restrict__ out,
                                 int n4) {
    int idx = blockIdx.x * blockDim.x + threadIdx.x;
    int stride = gridDim.x * blockDim.x;
    float4* __restrict__ out4 = reinterpret_cast<float4*>(out);
    for (int v = idx; v < n4; v += stride) {
        int wo4  = v & 511;
        int rest = v >> 9;
        int ho   = rest & 2047;
        int bc   = rest >> 11;
        float val = in[(bc << 18) + ((ho >> 2) << 9) + wo4];
        out4[v] = make_float4(val, val, val, val);
    }
}

extern "C" void kernel_launch(void* const* d_in, const int* in_sizes, int n_in,
                              void* d_out, int out_size, void* d_ws, size_t ws_size,
                              hipStream_t stream) {
    const float* in = (const float*)d_in[0];
    float* out = (float*)d_out;

    // out_size = 4*3*2048*2048 = 50331648 floats -> 12582912 float4 stores
    int n4 = out_size / 4;

    const int block = 256;
    // Cap grid at 256 CUs x 8 blocks/CU, grid-stride the rest.
    int grid = (n4 + block - 1) / block;
    if (grid > 2048) grid = 2048;

    upscale4x_kernel<<<grid, block, 0, stream>>>(in, out, n4);
}

// Round 2
// 36.677 us; speedup vs baseline: 1.1543x; 1.1543x over previous
//
#include <hip/hip_runtime.h>
#include <hip/hip_bf16.h>

// Problem: in_frame [B=4, C=3, H=512, W=512] float32, scale = 4.
// out [4, 3, 2048, 2048] float32, out[b,c,ho,wo] = in[b,c,ho/4,wo/4].
//
// One thread per INPUT pixel p:
//   wi = p & 511, rest = p >> 9  (rest = bc*512 + hi)
//   output rows  = 4*rest .. 4*rest+3   (since bc*2048 + 4*hi = 4*rest)
//   each row gets one float4 = 4 copies of in[p], at float4-col wi
//   (out row = 2048 floats = 512 float4; row stride in float4 units = 512)
//
// Loads: fully coalesced, each input byte read exactly once (12.6 MB).
// Stores: 4 x float4 per thread; each store instruction = contiguous 1 KB
// per wave (64 lanes x 16 B), rows 8 KB apart.

__global__ void upscale4x_kernel(const float* __restrict__ in,
                                 float* __restrict__ out,
                                 int npix) {
    int idx = blockIdx.x * blockDim.x + threadIdx.x;
    int stride = gridDim.x * blockDim.x;
    float4* __restrict__ out4 = reinterpret_cast<float4*>(out);
    for (int p = idx; p < npix; p += stride) {
        int wi   = p & 511;
        int rest = p >> 9;           // bc*512 + hi
        float val = in[p];
        float4 v4 = make_float4(val, val, val, val);
        int base = (rest << 11) + wi;  // (4*rest)*512 + wi, in float4 units
        out4[base]         = v4;
        out4[base + 512]   = v4;
        out4[base + 1024]  = v4;
        out4[base + 1536]  = v4;
    }
}

extern "C" void kernel_launch(void* const* d_in, const int* in_sizes, int n_in,
                              void* d_out, int out_size, void* d_ws, size_t ws_size,
                              hipStream_t stream) {
    const float* in = (const float*)d_in[0];
    float* out = (float*)d_out;

    int npix = in_sizes[0];          // 4*3*512*512 = 3145728

    const int block = 256;
    int grid = (npix + block - 1) / block;
    if (grid > 2048) grid = 2048;    // 256 CU x 8 blocks/CU; grid-stride rest

    upscale4x_kernel<<<grid, block, 0, stream>>>(in, out, npix);
}